// Round 9
// baseline (170.113 us; speedup 1.0000x reference)
//
#include <hip/hip_runtime.h>
#include <math.h>

#define NB 8
#define NLQ 1024
#define NLK 1024
#define ND 512
#define NH 8
#define MASKV -1e30f
#define LOG2E 1.44269504088896f
#define SHIFT2 32.0f   // fixed exp2-domain shift (replaces running max)

typedef unsigned short ushort_t;
typedef __attribute__((ext_vector_type(8))) _Float16 f16x8;
typedef __attribute__((ext_vector_type(8))) short bf16x8;
typedef __attribute__((ext_vector_type(16))) float f32x16;

__device__ __forceinline__ ushort_t f2h_bits(float f) {
    union { _Float16 h; ushort_t u; } v; v.h = (_Float16)f;
    return v.u;
}
__device__ __forceinline__ ushort_t f2bf(float f) {
    union { float f; unsigned u; } v; v.f = f;
    unsigned r = v.u + 0x7fffu + ((v.u >> 16) & 1u);
    return (ushort_t)(r >> 16);
}
__device__ __forceinline__ void gload16(const ushort_t* g, ushort_t* l) {
    __builtin_amdgcn_global_load_lds(
        (const __attribute__((address_space(1))) void*)g,
        (__attribute__((address_space(3))) void*)l, 16, 0, 0);
}
// pack bf16(p0) | bf16(p1)<<16, truncating (p >= 0)
__device__ __forceinline__ unsigned pack_bf16_trunc(float p0, float p1) {
    return __builtin_amdgcn_perm(__float_as_uint(p1), __float_as_uint(p0),
                                 0x07060302u);
}
// pack f16(a) | f16(b)<<16
__device__ __forceinline__ unsigned pack_f16(float a, float b) {
    return (unsigned)f2h_bits(a) | ((unsigned)f2h_bits(b) << 16);
}

// ---------------- W transpose: W (H,512,64) fp32 -> Wt (H,64,512) fp16
__global__ __launch_bounds__(256) void wsplit_kernel(
    const float* __restrict__ Wq, const float* __restrict__ Wk, const float* __restrict__ Wv,
    ushort_t* __restrict__ oq, ushort_t* __restrict__ ok, ushort_t* __restrict__ ov) {
    __shared__ float T[64][65];
    const int d0 = blockIdx.x * 64;
    const int h  = blockIdx.y;
    const int t  = blockIdx.z;
    const float* W = (t == 0) ? Wq : (t == 1) ? Wk : Wv;
    ushort_t* oh = (t == 0) ? oq : (t == 1) ? ok : ov;
    const int tid = threadIdx.x;
#pragma unroll
    for (int i = 0; i < 4; i++) {
        int r = (tid >> 4) + i * 16;
        int c = (tid & 15) * 4;
        float4 v = *(const float4*)&W[((size_t)h * ND + d0 + r) * 64 + c];
        *(float4*)&T[r][c] = v;
    }
    __syncthreads();
    const int e = tid & 63;
    const int dg = tid >> 6;
    ushort_t hs[16];
#pragma unroll
    for (int dd = 0; dd < 16; dd++) hs[dd] = f2h_bits(T[dg * 16 + dd][e]);
    size_t base = ((size_t)h * 64 + e) * ND + d0 + dg * 16;
#pragma unroll
    for (int c = 0; c < 2; c++) {
        uint4 wh;
        wh.x = (unsigned)hs[8*c+0] | ((unsigned)hs[8*c+1] << 16);
        wh.y = (unsigned)hs[8*c+2] | ((unsigned)hs[8*c+3] << 16);
        wh.z = (unsigned)hs[8*c+4] | ((unsigned)hs[8*c+5] << 16);
        wh.w = (unsigned)hs[8*c+6] | ((unsigned)hs[8*c+7] << 16);
        *(uint4*)&oh[base + 8 * c] = wh;
    }
}

// ---------------- fp16 MFMA projection, fused fp32->fp16 X conversion.
// All 3 tensors in one dispatch (z = t*8+b). 64l x 64e tile, BK=64.
// X staged via explicit fp32 loads + in-register cvt + ds_write (same swizzled
// fp16 layout as DMA); W staged via global_load_lds. Double-buffered with
// load / compute / write / barrier split so loads overlap MFMA.
// t=0: Q fp16 *LOG2E; t=1: K fp16; t=2: V bf16 transposed (b,h,e,l).
__global__ __launch_bounds__(256, 4) void proj_mfma_kernel(
    const float* __restrict__ Xq, const float* __restrict__ Xk,
    const float* __restrict__ Xv, const ushort_t* __restrict__ Wbase,
    ushort_t* __restrict__ Obase) {
    __shared__ ushort_t sX[2][4160];   // 8 groups x (8 rows x 64 + 8 pad)
    __shared__ ushort_t sW[2][4160];

    const int l0 = blockIdx.x * 64;
    const int h  = blockIdx.y;
    const int z  = blockIdx.z;
    const int t  = z >> 3;
    const int b  = z & 7;
    const int tid  = threadIdx.x;
    const int wave = tid >> 6;
    const int lane = tid & 63;
    const int l31  = lane & 31;
    const int hib  = lane >> 5;
    const size_t bh = (size_t)b * NH + h;

    const float* Xt = (t == 0) ? Xq : (t == 1) ? Xk : Xv;
    const float* gx = Xt + ((size_t)b * NLQ + l0) * ND;
    const ushort_t* gw = Wbase + (size_t)t * ((size_t)NH * 64 * ND)
                       + (size_t)h * 64 * ND;
    ushort_t* out = Obase + (size_t)t * ((size_t)NB * NH * NLQ * 64);

    const int srow = lane >> 3;            // 0..7
    const int schk = (lane & 7) ^ srow;    // swizzled source chunk
    // dest ushort offset within group (matches DMA's base + lane*16B):
    const int dslot = srow * 64 + (lane & 7) * 8;

    // W staging via DMA (fire-and-forget until barrier)
    auto stage_w = [&](int buf, int d0) {
#pragma unroll
        for (int i = 0; i < 2; i++) {
            int u = i * 4 + wave;
            int row = u * 8 + srow;
            gload16(gw + (size_t)row * ND + d0 + schk * 8, sW[buf] + u * 520);
        }
    };
    // X loads (fp32) into regs
    auto load_x = [&](int d0, float4* xa, float4* xb) {
#pragma unroll
        for (int i = 0; i < 2; i++) {
            int u = i * 4 + wave;
            int row = u * 8 + srow;
            const float* src = gx + (size_t)row * ND + d0 + schk * 8;
            xa[i] = *(const float4*)src;
            xb[i] = *(const float4*)(src + 4);
        }
    };
    // convert + write to LDS
    auto write_x = [&](int buf, const float4* xa, const float4* xb) {
#pragma unroll
        for (int i = 0; i < 2; i++) {
            int u = i * 4 + wave;
            uint4 w;
            w.x = pack_f16(xa[i].x, xa[i].y);
            w.y = pack_f16(xa[i].z, xa[i].w);
            w.z = pack_f16(xb[i].x, xb[i].y);
            w.w = pack_f16(xb[i].z, xb[i].w);
            *(uint4*)&sX[buf][u * 520 + dslot] = w;
        }
    };

    f32x16 acc;
#pragma unroll
    for (int i = 0; i < 16; i++) acc[i] = 0.f;

    const int arow = (wave >> 1) * 32 + l31;
    const int brow = (wave & 1) * 32 + l31;
    const int apad = (arow >> 3) * 520 + (arow & 7) * 64;
    const int bpad = (brow >> 3) * 520 + (brow & 7) * 64;
    const int sw = l31 & 7;

    // prologue: stage buffer 0
    {
        float4 xa[2], xb[2];
        load_x(0, xa, xb);
        stage_w(0, 0);
        write_x(0, xa, xb);
    }
    __syncthreads();
    int cur = 0;
    for (int kc = 0; kc < 8; kc++) {
        float4 xa[2], xb[2];
        if (kc < 7) {
            load_x((kc + 1) * 64, xa, xb);     // loads in flight during MFMA
            stage_w(cur ^ 1, (kc + 1) * 64);
        }
#pragma unroll
        for (int c = 0; c < 4; c++) {
            const int pc = ((2 * c + hib) ^ sw) * 8;
            f16x8 xh = *(const f16x8*)&sX[cur][apad + pc];
            f16x8 wh = *(const f16x8*)&sW[cur][bpad + pc];
            acc = __builtin_amdgcn_mfma_f32_32x32x16_f16(xh, wh, acc, 0, 0, 0);
        }
        if (kc < 7) write_x(cur ^ 1, xa, xb);
        __syncthreads();
        cur ^= 1;
    }

    if (t < 2) {
        const float scale = (t == 0) ? LOG2E : 1.f;
        const size_t obase = (bh * NLQ + l0) * 64;
        const int e = (wave & 1) * 32 + l31;
#pragma unroll
        for (int r = 0; r < 16; r++) {
            int l = (wave >> 1) * 32 + (r & 3) + 8 * (r >> 2) + 4 * hib;
            out[obase + (size_t)l * 64 + e] = f2h_bits(acc[r] * scale);
        }
    } else {
        // V: bf16, transposed via LDS (staging buffers are free after last barrier)
        ushort_t (*T)[68] = (ushort_t(*)[68])sX;
        const int e = (wave & 1) * 32 + l31;
#pragma unroll
        for (int r = 0; r < 16; r++) {
            int l = (wave >> 1) * 32 + (r & 3) + 8 * (r >> 2) + 4 * hib;
            T[e][l] = f2bf(acc[r]);
        }
        __syncthreads();
        const int e2 = tid >> 2;
        const int lc = (tid & 3) * 16;
        size_t base = (bh * 64 + e2) * NLK + l0 + lc;
        *(uint4*)&out[base]     = *(const uint4*)&T[e2][lc];
        *(uint4*)&out[base + 8] = *(const uint4*)&T[e2][lc + 8];
    }
}

// ---------------- MFMA flash attention: fp16 QK^T, fixed-shift exp2 softmax
// (no running max; bias does mask + shift via MFMA C-init), bf16 PV.
// 256 threads (4 waves, 128 q), grid 512 (idx&63 = bh for XCD locality).
// DMA staging with 16B/8-row group padding (bank-conflict-free).
__global__ __launch_bounds__(256, 4) void attn_kernel(
    const ushort_t* __restrict__ Qf, const ushort_t* __restrict__ Kf,
    const ushort_t* __restrict__ Vt, const float* __restrict__ maskp,
    float* __restrict__ Op) {
    __shared__ ushort_t sK[2][4160];
    __shared__ ushort_t sV[2][4160];
    __shared__ float sBias[1024];

    const int idx = blockIdx.x;
    const int bh_i = idx & 63;
    const int qc  = idx >> 6;          // 0..7
    const int b = bh_i >> 3, h = bh_i & 7;
    const size_t bh = (size_t)b * NH + h;

    const int tid  = threadIdx.x;
    const int wave = tid >> 6;
    const int lane = tid & 63;
    const int l31  = lane & 31;
    const int hib  = lane >> 5;
    const int q = qc * 128 + wave * 32 + l31;
    const int sw = l31 & 7;

    // bias = mask ? -SHIFT2 : -1e30  (exp2-domain shift + mask in one constant)
    {
        const float* mrow = maskp + ((size_t)b << 10);
        float4 m0 = *(const float4*)&mrow[tid * 4];
        float4 bi;
        bi.x = (m0.x > 0.5f) ? -SHIFT2 : MASKV;
        bi.y = (m0.y > 0.5f) ? -SHIFT2 : MASKV;
        bi.z = (m0.z > 0.5f) ? -SHIFT2 : MASKV;
        bi.w = (m0.w > 0.5f) ? -SHIFT2 : MASKV;
        *(float4*)&sBias[tid * 4] = bi;
    }

    f16x8 qh[4];
    {
        const ushort_t* ph = Qf + (bh * NLQ + q) * 64 + hib * 8;
#pragma unroll
        for (int c = 0; c < 4; c++) qh[c] = *(const f16x8*)(ph + c * 16);
    }

    const int srow = lane >> 3;
    const int schk = (lane & 7) ^ srow;

    // K rows permuted (storage row s holds key swap23(s)); V natural; group-padded
    auto stage = [&](int buf, int k0) {
#pragma unroll
        for (int n = 0; n < 4; n++) {
            int u = wave + n * 4;           // 0..15, uniform per wave
            if (u < 8) {
                int row = u * 8 + srow;
                int key = (row & ~12) | ((row & 4) << 1) | ((row & 8) >> 1);
                gload16(Kf + ((bh << 10) + k0 + key) * 64 + schk * 8,
                        sK[buf] + u * 520);
            } else {
                int u8 = u - 8;
                int row = u8 * 8 + srow;
                gload16(Vt + ((bh << 6) + row) * NLK + k0 + schk * 8,
                        sV[buf] + u8 * 520);
            }
        }
    };

    f32x16 O0, O1;
#pragma unroll
    for (int i = 0; i < 16; i++) { O0[i] = 0.f; O1[i] = 0.f; }
    float lrun = 0.f;

    const int rp0 = (l31 >> 3) * 520 + (l31 & 7) * 64;   // rows 0..31
    const int rp1 = rp0 + 4 * 520;                        // rows 32..63

    stage(0, 0);
    __syncthreads();
    int cur = 0;

    for (int t = 0; t < 16; t++) {
        const int k0 = t << 6;
        if (t < 15) stage(cur ^ 1, k0 + 64);

        // S init = bias (C-operand); quad g of half s holds keys
        // k0 + 32s + 16(g>>1) + 8hib + 4(g&1) + {0..3}
        f32x16 S0, S1;
#pragma unroll
        for (int g = 0; g < 4; g++) {
            const int kb = k0 + 16 * (g >> 1) + 8 * hib + 4 * (g & 1);
            float4 b0 = *(const float4*)&sBias[kb];
            float4 b1 = *(const float4*)&sBias[kb + 32];
            S0[4 * g + 0] = b0.x; S0[4 * g + 1] = b0.y;
            S0[4 * g + 2] = b0.z; S0[4 * g + 3] = b0.w;
            S1[4 * g + 0] = b1.x; S1[4 * g + 1] = b1.y;
            S1[4 * g + 2] = b1.z; S1[4 * g + 3] = b1.w;
        }
#pragma unroll
        for (int c = 0; c < 4; c++) {
            const int pc = ((2 * c + hib) ^ sw) * 8;
            f16x8 a0 = *(const f16x8*)&sK[cur][rp0 + pc];
            f16x8 a1 = *(const f16x8*)&sK[cur][rp1 + pc];
            S0 = __builtin_amdgcn_mfma_f32_32x32x16_f16(a0, qh[c], S0, 0, 0, 0);
            S1 = __builtin_amdgcn_mfma_f32_32x32x16_f16(a1, qh[c], S1, 0, 0, 0);
        }

        // p = exp2(S + bias); pack to bf16 (fp32 range -> no overflow, no max needed)
        unsigned pq[8][2];
#pragma unroll
        for (int g = 0; g < 8; g++) {
            float p0, p1, p2, p3;
            if (g < 4) {
                p0 = __builtin_amdgcn_exp2f(S0[4*g+0]);
                p1 = __builtin_amdgcn_exp2f(S0[4*g+1]);
                p2 = __builtin_amdgcn_exp2f(S0[4*g+2]);
                p3 = __builtin_amdgcn_exp2f(S0[4*g+3]);
            } else {
                p0 = __builtin_amdgcn_exp2f(S1[4*(g-4)+0]);
                p1 = __builtin_amdgcn_exp2f(S1[4*(g-4)+1]);
                p2 = __builtin_amdgcn_exp2f(S1[4*(g-4)+2]);
                p3 = __builtin_amdgcn_exp2f(S1[4*(g-4)+3]);
            }
            lrun += (p0 + p1) + (p2 + p3);
            pq[g][0] = pack_bf16_trunc(p0, p1);
            pq[g][1] = pack_bf16_trunc(p2, p3);
        }

        // O^T += V^T · P^T  (bf16; P fragment for chunk c = lane-local quads 2c,2c+1)
#pragma unroll
        for (int c = 0; c < 4; c++) {
            union { unsigned u[4]; bf16x8 v; } pf;
            pf.u[0] = pq[2 * c][0];     pf.u[1] = pq[2 * c][1];
            pf.u[2] = pq[2 * c + 1][0]; pf.u[3] = pq[2 * c + 1][1];
            const int pc = ((2 * c + hib) ^ sw) * 8;
            bf16x8 v0 = *(const bf16x8*)&sV[cur][rp0 + pc];
            bf16x8 v1 = *(const bf16x8*)&sV[cur][rp1 + pc];
            O0 = __builtin_amdgcn_mfma_f32_32x32x16_bf16(v0, pf.v, O0, 0, 0, 0);
            O1 = __builtin_amdgcn_mfma_f32_32x32x16_bf16(v1, pf.v, O1, 0, 0, 0);
        }
        __syncthreads();
        cur ^= 1;
    }

    lrun += __shfl_xor(lrun, 32);     // other key-half lives in lane^32
    const float linv = 1.f / lrun;
    float* obase = Op + ((size_t)(b * NLQ + q)) * (NH * 64) + h * 64;
#pragma unroll
    for (int me = 0; me < 2; me++) {
#pragma unroll
        for (int g = 0; g < 4; g++) {
            int e0 = me * 32 + 8 * g + 4 * hib;
            float4 o;
            if (me == 0) {
                o.x = O0[4 * g + 0] * linv; o.y = O0[4 * g + 1] * linv;
                o.z = O0[4 * g + 2] * linv; o.w = O0[4 * g + 3] * linv;
            } else {
                o.x = O1[4 * g + 0] * linv; o.y = O1[4 * g + 1] * linv;
                o.z = O1[4 * g + 2] * linv; o.w = O1[4 * g + 3] * linv;
            }
            *(float4*)&obase[e0] = o;
        }
    }
}

// ---------------- LayerNorm (unchanged).
__global__ __launch_bounds__(256) void ln_kernel(const float* __restrict__ X,
                                                 const float* __restrict__ gamma,
                                                 const float* __restrict__ beta,
                                                 float* __restrict__ out) {
    const int row = blockIdx.x * 4 + (threadIdx.x >> 6);
    const int lane = threadIdx.x & 63;
    const float* x = &X[(size_t)row * 512];
    float4 v0 = *(const float4*)&x[lane * 8];
    float4 v1 = *(const float4*)&x[lane * 8 + 4];
    float sum = v0.x + v0.y + v0.z + v0.w + v1.x + v1.y + v1.z + v1.w;
    float sq = v0.x * v0.x + v0.y * v0.y + v0.z * v0.z + v0.w * v0.w
             + v1.x * v1.x + v1.y * v1.y + v1.z * v1.z + v1.w * v1.w;
#pragma unroll
    for (int off = 32; off > 0; off >>= 1) {
        sum += __shfl_down(sum, off);
        sq  += __shfl_down(sq, off);
    }
    sum = __shfl(sum, 0);
    sq  = __shfl(sq, 0);
    const float mean = sum * (1.f / 512.f);
    const float var = sq * (1.f / 512.f) - mean * mean;
    const float rstd = rsqrtf(var + 1e-14f);
    const float g = gamma[0], be = beta[0];
    float* o = &out[(size_t)row * 512];
    float4 r0, r1;
    r0.x = (v0.x - mean) * rstd * g + be;  r0.y = (v0.y - mean) * rstd * g + be;
    r0.z = (v0.z - mean) * rstd * g + be;  r0.w = (v0.w - mean) * rstd * g + be;
    r1.x = (v1.x - mean) * rstd * g + be;  r1.y = (v1.y - mean) * rstd * g + be;
    r1.z = (v1.z - mean) * rstd * g + be;  r1.w = (v1.w - mean) * rstd * g + be;
    *(float4*)&o[lane * 8] = r0;
    *(float4*)&o[lane * 8 + 4] = r1;
}

extern "C" void kernel_launch(void* const* d_in, const int* in_sizes, int n_in,
                              void* d_out, int out_size, void* d_ws, size_t ws_size,
                              hipStream_t stream) {
    const float* query = (const float*)d_in[0];
    const float* key_t = (const float*)d_in[1];
    const float* value = (const float*)d_in[2];
    const float* mask  = (const float*)d_in[3];
    const float* Wq    = (const float*)d_in[4];
    const float* Wk    = (const float*)d_in[5];
    const float* Wv    = (const float*)d_in[6];
    const float* gamma = (const float*)d_in[7];
    const float* beta  = (const float*)d_in[8];
    float* out = (float*)d_out;

    const size_t A = (size_t)NB * NLQ * ND;        // 4,194,304 (= per-tensor size)
    const size_t WS = (size_t)NH * 64 * ND;        // 262,144
    ushort_t* Qf = (ushort_t*)d_ws;                // fp16 (b,h,l,64), *log2e
    ushort_t* Kf = Qf + A;                          // fp16 (b,h,l,64)
    ushort_t* Vt = Qf + 2 * A;                      // bf16 (b,h,e,l)
    ushort_t* Wt = Qf + 3 * A;                      // fp16 Wt, 3 tensors contiguous

    wsplit_kernel<<<dim3(ND / 64, NH, 3), 256, 0, stream>>>(
        Wq, Wk, Wv, Wt, Wt + WS, Wt + 2 * WS);

    proj_mfma_kernel<<<dim3(NLQ / 64, NH, 24), 256, 0, stream>>>(
        query, key_t, value, Wt, Qf);

    attn_kernel<<<512, 256, 0, stream>>>(Qf, Kf, Vt, mask, out);

    ln_kernel<<<(NB * NLQ) / 4, 256, 0, stream>>>(out, gamma, beta, out);
}